// Round 2
// baseline (755.647 us; speedup 1.0000x reference)
//
#include <hip/hip_runtime.h>
#include <hip/hip_bf16.h>

// SepConv: relu -> dw3x3 -> pw1x1 -> BN (inference), NHWC fp32 in/out.
// B=16, H=W=224, C=96.
//
// Structure (vs the 64-px-per-block 688us version):
//  - weights/BN staged in LDS ONCE per block (was: every 64-px tile)
//  - depthwise computed directly into MFMA A-fragment registers by the
//    owning lane (lane l -> pixel l&15, channels (l>>4)*8 + 32*ks)
//    -> no s_dw LDS round-trip, no __syncthreads in the main loop
//  - each wave independently grid-strides over 16-px tiles (224 = 14*16,
//    tiles never straddle a row -> h-halo checks are wave-uniform)
//  - XCD banding: block%8 owns a contiguous 448-row band so vertical
//    halo re-reads hit the same XCD's L2

#define BATCH 16
#define HH 224
#define WWD 224
#define CC 96
#define ROWS (BATCH*HH)            // 3584
#define TPR 14                     // 16-px tiles per row
#define NTILES (ROWS*TPR)          // 50176
#define NTHREADS 256
#define WAVES 4
#define NBLOCKS 1024               // 8 XCD bands * 128 blocks
#define NXCD 8
#define TILES_PER_BAND (NTILES/NXCD)           // 6272
#define WAVES_PER_BAND ((NBLOCKS/NXCD)*WAVES)  // 512
#define PAD 104                    // padded LDS row (bf16 elems)

typedef __attribute__((ext_vector_type(8))) short short8;
typedef __attribute__((ext_vector_type(4))) float f32x4;

__device__ __forceinline__ unsigned short f2bf(float f){
    union{float f; unsigned u;} v; v.f = f;
    unsigned r = v.u + 0x7fffu + ((v.u >> 16) & 1u);   // RTNE
    return (unsigned short)(r >> 16);
}

// One 3x3 tap: 8 channels for each of the 3 k-steps (24 ch total).
// xp: global, per-lane pixel base (+ quad*8 ch). wp: LDS weight row (+ quad*8).
__device__ __forceinline__ void tap_fma(const float* __restrict__ xp,
                                        const float* wp,
                                        float acc[3][8])
{
    #pragma unroll
    for (int ks = 0; ks < 3; ++ks) {
        float4 x0 = *reinterpret_cast<const float4*>(xp + ks*32);
        float4 x1 = *reinterpret_cast<const float4*>(xp + ks*32 + 4);
        float4 w0 = *reinterpret_cast<const float4*>(wp + ks*32);
        float4 w1 = *reinterpret_cast<const float4*>(wp + ks*32 + 4);
        acc[ks][0] += fmaxf(x0.x, 0.f) * w0.x;
        acc[ks][1] += fmaxf(x0.y, 0.f) * w0.y;
        acc[ks][2] += fmaxf(x0.z, 0.f) * w0.z;
        acc[ks][3] += fmaxf(x0.w, 0.f) * w0.w;
        acc[ks][4] += fmaxf(x1.x, 0.f) * w1.x;
        acc[ks][5] += fmaxf(x1.y, 0.f) * w1.y;
        acc[ks][6] += fmaxf(x1.z, 0.f) * w1.z;
        acc[ks][7] += fmaxf(x1.w, 0.f) * w1.w;
    }
}

__global__ __launch_bounds__(NTHREADS, 4) void sepconv_kernel(
    const float* __restrict__ x,
    const float* __restrict__ dwk,    // (3,3,1,96)
    const float* __restrict__ dwb,    // (96)
    const float* __restrict__ pwk,    // (1,1,96,96) [ci][co]
    const float* __restrict__ pwb,    // (96)
    const float* __restrict__ gma,
    const float* __restrict__ bta,
    const float* __restrict__ mmean,
    const float* __restrict__ mvar,
    float* __restrict__ out)
{
    __shared__ __align__(16) unsigned short s_pwT[CC][PAD];  // pw^T [co][ci] bf16, ~20 KB
    __shared__ __align__(16) float s_dwk[9][CC];             // dw weights fp32
    __shared__ __align__(16) float s_dwb[CC];
    __shared__ __align__(16) float s_scale[CC];
    __shared__ __align__(16) float s_shift[CC];

    const int t = threadIdx.x;

    // ---- one-time staging (amortized over ~12 tiles/wave) ----
    for (int e = t; e < CC*CC; e += NTHREADS) {
        int ci = e / CC;
        int co = e - ci*CC;
        s_pwT[co][ci] = f2bf(pwk[e]);      // coalesced read, transposed LDS write
    }
    for (int e = t; e < 9*CC; e += NTHREADS)
        (&s_dwk[0][0])[e] = dwk[e];
    if (t < CC) {
        s_dwb[t] = dwb[t];
        float sc = gma[t] / sqrtf(mvar[t] + 1e-3f);
        s_scale[t] = sc;
        s_shift[t] = (pwb[t] - mmean[t]) * sc + bta[t];
    }
    __syncthreads();
    // no barriers below this point — waves run independently

    const int wave = t >> 6;
    const int lane = t & 63;
    const int col  = lane & 15;      // m-row of A / n-col of B/D
    const int quad = lane >> 4;      // k-subchunk owner

    // BN constants for this lane's 6 output-channel tiles
    float scv[6], shv[6];
    #pragma unroll
    for (int nt = 0; nt < 6; ++nt) {
        scv[nt] = s_scale[nt*16 + col];
        shv[nt] = s_shift[nt*16 + col];
    }

    // XCD banding: block%8 works a contiguous 448-row band of the image
    const int xcd = blockIdx.x & (NXCD-1);
    const int lb  = blockIdx.x >> 3;               // 0..127 within band
    const int gw  = lb*WAVES + wave;               // 0..511 within band
    const int Tend = (xcd+1)*TILES_PER_BAND;

    for (int T = xcd*TILES_PER_BAND + gw; T < Tend; T += WAVES_PER_BAND) {
        const int rrow = T / TPR;                  // global row = b*224 + h
        const int wt   = T - rrow*TPR;
        const int h    = rrow % HH;
        const int w_me = wt*16 + col;              // this lane's pixel column
        const float* xb = x + (size_t)(rrow*WWD + w_me)*CC + quad*8;

        // ---- depthwise 3x3, fp32, straight into A-fragment ownership ----
        float acc[3][8];
        #pragma unroll
        for (int ks = 0; ks < 3; ++ks) {
            float4 b0 = *reinterpret_cast<const float4*>(&s_dwb[ks*32 + quad*8]);
            float4 b1 = *reinterpret_cast<const float4*>(&s_dwb[ks*32 + quad*8 + 4]);
            acc[ks][0]=b0.x; acc[ks][1]=b0.y; acc[ks][2]=b0.z; acc[ks][3]=b0.w;
            acc[ks][4]=b1.x; acc[ks][5]=b1.y; acc[ks][6]=b1.z; acc[ks][7]=b1.w;
        }

        #pragma unroll
        for (int kh = -1; kh <= 1; ++kh) {
            const int h2 = h + kh;
            if ((unsigned)h2 >= HH) continue;      // wave-uniform branch
            const float* rp = xb + kh*(WWD*CC);
            const float* wr = &s_dwk[(kh+1)*3][0] + quad*8;
            if (w_me >= 1)       tap_fma(rp - CC, wr,        acc);  // kw=-1
                                 tap_fma(rp,      wr + CC,   acc);  // kw= 0
            if (w_me <= WWD-2)   tap_fma(rp + CC, wr + 2*CC, acc);  // kw=+1
        }

        // ---- pack to bf16 A-fragments ----
        short8 afr[3];
        #pragma unroll
        for (int ks = 0; ks < 3; ++ks) {
            union { short8 v; unsigned u[4]; } pk;
            #pragma unroll
            for (int j = 0; j < 4; ++j)
                pk.u[j] = (unsigned)f2bf(acc[ks][2*j])
                        | ((unsigned)f2bf(acc[ks][2*j+1]) << 16);
            afr[ks] = pk.v;
        }

        // ---- pointwise GEMM: 6 co-tiles x 3 k-steps of MFMA + BN epilogue ----
        float* ob = out + (size_t)(T*16 + quad*4)*CC + col;
        #pragma unroll
        for (int nt = 0; nt < 6; ++nt) {
            f32x4 macc = {0.f, 0.f, 0.f, 0.f};
            #pragma unroll
            for (int ks = 0; ks < 3; ++ks) {
                short8 bfr = *reinterpret_cast<const short8*>(
                    &s_pwT[nt*16 + col][ks*32 + quad*8]);
                macc = __builtin_amdgcn_mfma_f32_16x16x32_bf16(afr[ks], bfr, macc, 0, 0, 0);
            }
            #pragma unroll
            for (int r2 = 0; r2 < 4; ++r2)
                ob[r2*CC + nt*16] = macc[r2]*scv[nt] + shv[nt];
        }
    }
}

extern "C" void kernel_launch(void* const* d_in, const int* in_sizes, int n_in,
                              void* d_out, int out_size, void* d_ws, size_t ws_size,
                              hipStream_t stream)
{
    sepconv_kernel<<<NBLOCKS, NTHREADS, 0, stream>>>(
        (const float*)d_in[0],
        (const float*)d_in[1],
        (const float*)d_in[2],
        (const float*)d_in[3],
        (const float*)d_in[4],
        (const float*)d_in[5],
        (const float*)d_in[6],
        (const float*)d_in[7],
        (const float*)d_in[8],
        (float*)d_out);
}